// Round 1
// 90.240 us; speedup vs baseline: 1.0598x; 1.0598x over previous
//
#include <hip/hip_runtime.h>
#include <stdint.h>

// TrajectoryFK: L=65536 timesteps, J=22 joints, 6D-rotation inputs (fp32).
// R7: occupancy-driven split. Old fk_main ran at 1 block/CU (4 waves/CU,
// 1 wave/SIMD) -> every DS/VMEM/dep-chain latency fully exposed.
// New: K1 fk_scan materializes the block-local prefix f (3 MB roundtrip,
// removes old K2's re-derived elem_transform+block_scan), K2 fk_tree runs
// 1024 blocks (16 waves/CU): 64 timesteps x 4 role-waves, each wave owns a
// subtree partition; positions assembled in LDS, stored coalesced.

#define LTOT 65536
#define ROW 132                 // 22 joints * 6 floats per timestep (528 B)
#define P1B 256                 // threads per block
#define NBLK (LTOT / P1B)       // 256 scan blocks
#define TB 64                   // timesteps per tree block
#define NTB (LTOT / TB)         // 1024 tree blocks

struct Aff { float A[9]; float b[3]; };
struct V3 { float x, y, z; };

__device__ __forceinline__ void d6_to_mat(float a0, float a1, float a2,
                                          float a3, float a4, float a5,
                                          float R[9]) {
  // Gram-Schmidt; columns of R are b1,b2,b3 (row-major R[r*3+c]).
  float n1 = sqrtf(a0 * a0 + a1 * a1 + a2 * a2);
  float i1 = 1.0f / fmaxf(n1, 1e-12f);
  float b10 = a0 * i1, b11 = a1 * i1, b12 = a2 * i1;
  float d = b10 * a3 + b11 * a4 + b12 * a5;
  float c0 = a3 - d * b10, c1 = a4 - d * b11, c2 = a5 - d * b12;
  float n2 = sqrtf(c0 * c0 + c1 * c1 + c2 * c2);
  float i2 = 1.0f / fmaxf(n2, 1e-12f);
  float b20 = c0 * i2, b21 = c1 * i2, b22 = c2 * i2;
  float b30 = b11 * b22 - b12 * b21;
  float b31 = b12 * b20 - b10 * b22;
  float b32 = b10 * b21 - b11 * b20;
  R[0] = b10; R[1] = b20; R[2] = b30;
  R[3] = b11; R[4] = b21; R[5] = b31;
  R[6] = b12; R[7] = b22; R[8] = b32;
}

__device__ __forceinline__ void mat_mul(const float A[9], const float B[9], float C[9]) {
#pragma unroll
  for (int i = 0; i < 3; ++i)
#pragma unroll
    for (int j = 0; j < 3; ++j)
      C[i * 3 + j] = A[i * 3 + 0] * B[0 + j] + A[i * 3 + 1] * B[3 + j] + A[i * 3 + 2] * B[6 + j];
}

__device__ __forceinline__ void mat_vec(const float A[9], float x, float y, float z,
                                        float& ox, float& oy, float& oz) {
  ox = A[0] * x + A[1] * y + A[2] * z;
  oy = A[3] * x + A[4] * y + A[5] * z;
  oz = A[6] * x + A[7] * y + A[8] * z;
}

__device__ __forceinline__ void compose(const Aff& P, const Aff& T, Aff& O) {
  mat_mul(P.A, T.A, O.A);
  float bx, by, bz;
  mat_vec(P.A, T.b[0], T.b[1], T.b[2], bx, by, bz);
  O.b[0] = P.b[0] + bx; O.b[1] = P.b[1] + by; O.b[2] = P.b[2] + bz;
}

__device__ __forceinline__ void aff_identity(Aff& v) {
  v.A[0] = 1.f; v.A[1] = 0.f; v.A[2] = 0.f;
  v.A[3] = 0.f; v.A[4] = 1.f; v.A[5] = 0.f;
  v.A[6] = 0.f; v.A[7] = 0.f; v.A[8] = 1.f;
  v.b[0] = 0.f; v.b[1] = 0.f; v.b[2] = 0.f;
}

// Inclusive Hillis-Steele scan across the 64-lane wave.
__device__ __forceinline__ void wave_scan(Aff& v, int lane) {
#pragma unroll
  for (int s = 1; s < 64; s <<= 1) {
    Aff u;
#pragma unroll
    for (int k = 0; k < 9; ++k) u.A[k] = __shfl_up(v.A[k], s, 64);
#pragma unroll
    for (int k = 0; k < 3; ++k) u.b[k] = __shfl_up(v.b[k], s, 64);
    if (lane >= s) { Aff t; compose(u, v, t); v = t; }
  }
}

// Block-local scan: wave scan + cross-wave LDS compose -> inclusive prefix f.
__device__ __forceinline__ void block_scan(Aff& v, int lane, int wid,
                                           float (*sagg)[12], Aff& f) {
  wave_scan(v, lane);
  if (lane == 63) {
#pragma unroll
    for (int k = 0; k < 9; ++k) sagg[wid][k] = v.A[k];
#pragma unroll
    for (int k = 0; k < 3; ++k) sagg[wid][9 + k] = v.b[k];
  }
  __syncthreads();
  Aff pre; aff_identity(pre);
  for (int w = 0; w < wid; ++w) {   // <=3 compositions, broadcast LDS reads
    Aff g, t2;
#pragma unroll
    for (int k = 0; k < 9; ++k) g.A[k] = sagg[w][k];
#pragma unroll
    for (int k = 0; k < 3; ++k) g.b[k] = sagg[w][9 + k];
    compose(pre, g, t2); pre = t2;
  }
  compose(pre, v, f);
}

// Element transform for timestep t: T_t = (d_t, d_t @ v_t).
__device__ __forceinline__ void elem_transform(const float* __restrict__ pred,
                                               int t, Aff& v) {
  const float4* q4 = (const float4*)(pred + (size_t)t * ROW);  // 16B-aligned
  float4 qa = q4[0];   // j0: v0 v1 v2 .
  float4 qb = q4[1];   // . . e0 e1
  float4 qc = q4[2];   // e2 e3 e4 e5
  d6_to_mat(qb.z, qb.w, qc.x, qc.y, qc.z, qc.w, v.A);          // d_t
  mat_vec(v.A, qa.x, qa.y, qa.z, v.b[0], v.b[1], v.b[2]);      // d_t @ v_t
}

// rot child: Rj = Rp @ M(q[j])
__device__ __forceinline__ void rotj(const float* __restrict__ q, int j,
                                     const float Rp[9], float Rj[9]) {
  const float2* qq = (const float2*)(q + j * 6);   // 8B-aligned
  float2 w0 = qq[0], w1 = qq[1], w2 = qq[2];
  float Mx[9];
  d6_to_mat(w0.x, w0.y, w1.x, w1.y, w2.x, w2.y, Mx);
  mat_mul(Rp, Mx, Rj);
}

// pos child: pj = pp + Rp @ offs[j]
__device__ __forceinline__ V3 childpos(const float* __restrict__ offs, int j,
                                       V3 pp, const float Rp[9]) {
  float ox, oy, oz;
  mat_vec(Rp, offs[j * 3 + 0], offs[j * 3 + 1], offs[j * 3 + 2], ox, oy, oz);
  V3 r; r.x = pp.x + ox; r.y = pp.y + oy; r.z = pp.z + oz; return r;
}

__device__ __forceinline__ void stp(float (*spos)[66], int lane, int j, V3 p) {
  spos[lane][j * 3 + 0] = p.x;   // stride-66 dword writes: 2-way bank alias, free
  spos[lane][j * 3 + 1] = p.y;
  spos[lane][j * 3 + 2] = p.z;
}

// ---------------- K1: block-local prefixes f + block aggregates ----------
__global__ __launch_bounds__(P1B) void fk_scan(const float* __restrict__ pred,
                                               float* __restrict__ agg,
                                               float* __restrict__ floc) {
  int tid = threadIdx.x;
  int t = blockIdx.x * P1B + tid;
  int lane = tid & 63, wid = tid >> 6;
  __shared__ float sagg[P1B / 64][12];

  Aff v, f;
  elem_transform(pred, t, v);
  block_scan(v, lane, wid, sagg, f);

  float4* fp = (float4*)(floc + (size_t)t * 12);   // 48B stride, 16B-aligned
  fp[0] = make_float4(f.A[0], f.A[1], f.A[2], f.A[3]);
  fp[1] = make_float4(f.A[4], f.A[5], f.A[6], f.A[7]);
  fp[2] = make_float4(f.A[8], f.b[0], f.b[1], f.b[2]);

  if (tid == P1B - 1) {          // f of last thread == block aggregate
    float4* a = (float4*)(agg + (size_t)blockIdx.x * 12);
    a[0] = make_float4(f.A[0], f.A[1], f.A[2], f.A[3]);
    a[1] = make_float4(f.A[4], f.A[5], f.A[6], f.A[7]);
    a[2] = make_float4(f.A[8], f.b[0], f.b[1], f.b[2]);
  }
}

// ---------------- K2: agg scan + compose + 4-way subtree split -----------
// 1024 blocks x 256 threads: 64 timesteps per block, wave w = role w.
// Roles: 0: {0,1,2,5,8,11}  1: {4,7,10, 3,6,9,12,15}
//        2: {13,16,18,20}   3: {14,17,19,21}  (2/3 recompute cheap 3->6->9)
__global__ __launch_bounds__(P1B, 4) void fk_tree(const float* __restrict__ pred,
                                                  const float* __restrict__ offs,
                                                  const float* __restrict__ agg,
                                                  const float* __restrict__ floc,
                                                  float* __restrict__ out) {
  int tid = threadIdx.x;
  int lane = tid & 63, wid = tid >> 6;
  int t = blockIdx.x * TB + lane;

  __shared__ float sagg[P1B / 64][12];
  __shared__ float ebs[12];
  __shared__ __align__(16) float spos[TB][66];   // 16.9 KB

  // Issue f load early; latency hides under the aggregate scan.
  Aff fv;
  {
    const float4* fp = (const float4*)(floc + (size_t)t * 12);
    float4 a0 = fp[0], a1 = fp[1], a2 = fp[2];
    fv.A[0] = a0.x; fv.A[1] = a0.y; fv.A[2] = a0.z; fv.A[3] = a0.w;
    fv.A[4] = a1.x; fv.A[5] = a1.y; fv.A[6] = a1.z; fv.A[7] = a1.w;
    fv.A[8] = a2.x; fv.b[0] = a2.y; fv.b[1] = a2.z; fv.b[2] = a2.w;
  }

  // Redundant inclusive scan of the 256 block aggregates (12 KB, L2-hot).
  Aff v2;
  {
    const float4* a = (const float4*)(agg + (size_t)tid * 12);
    float4 a0 = a[0], a1 = a[1], a2 = a[2];
    v2.A[0] = a0.x; v2.A[1] = a0.y; v2.A[2] = a0.z; v2.A[3] = a0.w;
    v2.A[4] = a1.x; v2.A[5] = a1.y; v2.A[6] = a1.z; v2.A[7] = a1.w;
    v2.A[8] = a2.x; v2.b[0] = a2.y; v2.b[1] = a2.z; v2.b[2] = a2.w;
  }
  Aff incl;
  block_scan(v2, lane, wid, sagg, incl);

  int tb = blockIdx.x >> 2;              // parent P1B-block of this 64-tile
  if (tid == tb - 1) {                   // owner of the exclusive prefix
#pragma unroll
    for (int k = 0; k < 9; ++k) ebs[k] = incl.A[k];
#pragma unroll
    for (int k = 0; k < 3; ++k) ebs[9 + k] = incl.b[k];
  }
  __syncthreads();

  Aff eb;
  if (tb == 0) {
    aff_identity(eb);
  } else {
#pragma unroll
    for (int k = 0; k < 9; ++k) eb.A[k] = ebs[k];      // broadcast reads
#pragma unroll
    for (int k = 0; k < 3; ++k) eb.b[k] = ebs[9 + k];
  }

  Aff g; compose(eb, fv, g);             // global (R, root_pos) for timestep t
  const float* R = g.A;
  V3 p0; p0.x = g.b[0]; p0.y = g.b[1]; p0.z = g.b[2];
  const float* q = pred + (size_t)t * ROW;

  if (wid == 0) {
    stp(spos, lane, 0, p0);
    V3 p1 = childpos(offs, 1, p0, R);  stp(spos, lane, 1, p1);
    V3 p2 = childpos(offs, 2, p0, R);  stp(spos, lane, 2, p2);
    float r2[9]; rotj(q, 2, R, r2);
    V3 p5 = childpos(offs, 5, p2, r2); stp(spos, lane, 5, p5);
    float r5[9]; rotj(q, 5, r2, r5);
    V3 p8 = childpos(offs, 8, p5, r5); stp(spos, lane, 8, p8);
    float r8[9]; rotj(q, 8, r5, r8);
    V3 p11 = childpos(offs, 11, p8, r8); stp(spos, lane, 11, p11);
  } else if (wid == 1) {
    V3 p1 = childpos(offs, 1, p0, R);             // recomputed, not stored
    V3 p4 = childpos(offs, 4, p1, R);  stp(spos, lane, 4, p4);   // rots[1]=R
    float r4[9]; rotj(q, 4, R, r4);
    V3 p7 = childpos(offs, 7, p4, r4); stp(spos, lane, 7, p7);
    float r7[9]; rotj(q, 7, r4, r7);
    V3 p10 = childpos(offs, 10, p7, r7); stp(spos, lane, 10, p10);
    V3 p3 = childpos(offs, 3, p0, R);  stp(spos, lane, 3, p3);
    float r3[9]; rotj(q, 3, R, r3);
    V3 p6 = childpos(offs, 6, p3, r3); stp(spos, lane, 6, p6);
    float r6[9]; rotj(q, 6, r3, r6);
    V3 p9 = childpos(offs, 9, p6, r6); stp(spos, lane, 9, p9);
    float r9[9]; rotj(q, 9, r6, r9);
    V3 p12 = childpos(offs, 12, p9, r9); stp(spos, lane, 12, p12);
    float r12[9]; rotj(q, 12, r9, r12);
    V3 p15 = childpos(offs, 15, p12, r12); stp(spos, lane, 15, p15);
  } else {
    // shared prefix 3 -> 6 -> 9 (recomputed, not stored)
    V3 p3 = childpos(offs, 3, p0, R);
    float r3[9]; rotj(q, 3, R, r3);
    V3 p6 = childpos(offs, 6, p3, r3);
    float r6[9]; rotj(q, 6, r3, r6);
    V3 p9 = childpos(offs, 9, p6, r6);
    float r9[9]; rotj(q, 9, r6, r9);
    if (wid == 2) {
      V3 p13 = childpos(offs, 13, p9, r9); stp(spos, lane, 13, p13);
      float r13[9]; rotj(q, 13, r9, r13);
      V3 p16 = childpos(offs, 16, p13, r13); stp(spos, lane, 16, p16);
      float r16[9]; rotj(q, 16, r13, r16);
      V3 p18 = childpos(offs, 18, p16, r16); stp(spos, lane, 18, p18);
      float r18[9]; rotj(q, 18, r16, r18);
      V3 p20 = childpos(offs, 20, p18, r18); stp(spos, lane, 20, p20);
    } else {
      V3 p14 = childpos(offs, 14, p9, r9); stp(spos, lane, 14, p14);
      float r14[9]; rotj(q, 14, r9, r14);
      V3 p17 = childpos(offs, 17, p14, r14); stp(spos, lane, 17, p17);
      float r17[9]; rotj(q, 17, r14, r17);
      V3 p19 = childpos(offs, 19, p17, r17); stp(spos, lane, 19, p19);
      float r19[9]; rotj(q, 19, r17, r19);
      V3 p21 = childpos(offs, 21, p19, r19); stp(spos, lane, 21, p21);
    }
  }

  __syncthreads();
  // Coalesced store of 64 full rows (64*264 B) via flat float4 copy.
  const float4* sp = (const float4*)&spos[0][0];
  float4* op = (float4*)(out + (size_t)blockIdx.x * TB * 66);
#pragma unroll
  for (int k = 0; k < (TB * 66 / 4 + P1B - 1) / P1B; ++k) {  // 5 iters
    int idx = tid + k * P1B;
    if (idx < TB * 66 / 4) op[idx] = sp[idx];
  }
}

extern "C" void kernel_launch(void* const* d_in, const int* in_sizes, int n_in,
                              void* d_out, int out_size, void* d_ws, size_t ws_size,
                              hipStream_t stream) {
  const float* pred = (const float*)d_in[0];   // (L, 22, 6) fp32
  const float* offs = (const float*)d_in[1];   // (22, 3)    fp32
  float* out = (float*)d_out;                  // (L, 22, 3) fp32
  float* agg = (float*)d_ws;                   // 12 * NBLK floats (12 KB)
  float* floc = (float*)((char*)d_ws + 16384); // 12 * L floats (3 MB), 16B-aligned

  fk_scan<<<NBLK, P1B, 0, stream>>>(pred, agg, floc);
  fk_tree<<<NTB, P1B, 0, stream>>>(pred, offs, agg, floc, out);
}